// Round 1
// baseline (760.079 us; speedup 1.0000x reference)
//
#include <hip/hip_runtime.h>

// Antialiased bilinear downsample (JAX triangle filter, scale=1/4 both axes):
//   in  (2048, 6, 128, 96) fp32
//   out (2048, 6, 32, 24) fp32  (reshape to (-1,6,768) is a no-op on flat layout)
//
// Separable 8-tap filter per axis. Interior weights [1,3,5,7,7,5,3,1]/32.
// Edge outputs (o==0 / o==last) lose 2 taps and renormalize by 3.5.

#define IMG_H 128
#define IMG_W 96
#define ROUT_H 32
#define ROUT_W 24
#define LDSTRIDE 100   // staged input row stride in floats (400B, 16B-aligned, bank-uniform)
#define MIDSTRIDE 25   // intermediate row stride (odd -> conflict-free scalar access)

__global__ __launch_bounds__(256, 2)
void resize_aa_kernel(const float* __restrict__ x, float* __restrict__ out) {
    __shared__ float s_in[IMG_H * LDSTRIDE];    // 51200 B
    __shared__ float s_mid[IMG_H * MIDSTRIDE];  // 12800 B

    const int img = blockIdx.x;
    const int tid = threadIdx.x;
    const float* __restrict__ src = x + (size_t)img * (IMG_H * IMG_W);

    // ---- Stage: 3072 float4 chunks, fully coalesced global reads ----
    const float4* __restrict__ src4 = (const float4*)src;
#pragma unroll
    for (int k = 0; k < 12; ++k) {
        int f = tid + k * 256;          // chunk index, 24 chunks per row
        float4 g = src4[f];
        int row = f / 24;
        int c   = f - row * 24;
        *(float4*)(&s_in[row * LDSTRIDE + 4 * c]) = g;
    }
    __syncthreads();

    // ---- Phase 1: horizontal 96 -> 24, sliding float4 window in registers ----
    {
        int r = tid & 127;              // row (lane-contiguous within a wave)
        int h = tid >> 7;               // half: ow in [12h, 12h+12)
        const float* rowp = &s_in[r * LDSTRIDE];
        int c0 = 12 * h;

        float4 prev = (h == 0) ? make_float4(0.f, 0.f, 0.f, 0.f)
                               : *(const float4*)(rowp + 4 * (c0 - 1));
        float4 cur  = *(const float4*)(rowp + 4 * c0);
#pragma unroll
        for (int j = 0; j < 12; ++j) {
            int ow = c0 + j;
            float4 next = (ow + 1 < ROUT_W) ? *(const float4*)(rowp + 4 * (ow + 1))
                                            : make_float4(0.f, 0.f, 0.f, 0.f);
            // taps: prev.z prev.w cur.x cur.y cur.z cur.w next.x next.y
            float w0 = 1.f/32, w1 = 3.f/32, w2 = 5.f/32, w3 = 7.f/32,
                  w4 = 7.f/32, w5 = 5.f/32, w6 = 3.f/32, w7 = 1.f/32;
            if (ow == 0) {              // wave-uniform branch (ow uniform across lanes)
                const float s = 1.0f / 3.5f;
                w0 = 0.f;        w1 = 0.f;
                w2 = 0.625f * s; w3 = 0.875f * s; w4 = 0.875f * s;
                w5 = 0.625f * s; w6 = 0.375f * s; w7 = 0.125f * s;
            } else if (ow == ROUT_W - 1) {
                const float s = 1.0f / 3.5f;
                w0 = 0.125f * s; w1 = 0.375f * s; w2 = 0.625f * s;
                w3 = 0.875f * s; w4 = 0.875f * s; w5 = 0.625f * s;
                w6 = 0.f;        w7 = 0.f;
            }
            float acc = w0 * prev.z + w1 * prev.w
                      + w2 * cur.x  + w3 * cur.y + w4 * cur.z + w5 * cur.w
                      + w6 * next.x + w7 * next.y;
            s_mid[r * MIDSTRIDE + ow] = acc;
            prev = cur; cur = next;
        }
    }
    __syncthreads();

    // ---- Phase 2: vertical 128 -> 32, 3 outputs per thread ----
    float* __restrict__ dst = out + (size_t)img * (ROUT_H * ROUT_W);
#pragma unroll
    for (int k = 0; k < 3; ++k) {
        int idx = tid + k * 256;        // 0..767
        int oh = idx / ROUT_W;
        int ow = idx - oh * ROUT_W;
        int r0 = 4 * oh - 2;

        float w[8] = {1.f/32, 3.f/32, 5.f/32, 7.f/32, 7.f/32, 5.f/32, 3.f/32, 1.f/32};
        if (oh == 0) {
            const float s = 1.0f / 3.5f;
            w[0] = 0.f;        w[1] = 0.f;
            w[2] = 0.625f * s; w[3] = 0.875f * s; w[4] = 0.875f * s;
            w[5] = 0.625f * s; w[6] = 0.375f * s; w[7] = 0.125f * s;
        } else if (oh == ROUT_H - 1) {
            const float s = 1.0f / 3.5f;
            w[0] = 0.125f * s; w[1] = 0.375f * s; w[2] = 0.625f * s;
            w[3] = 0.875f * s; w[4] = 0.875f * s; w[5] = 0.625f * s;
            w[6] = 0.f;        w[7] = 0.f;
        }
        float acc = 0.f;
#pragma unroll
        for (int t = 0; t < 8; ++t) {
            int r = r0 + t;
            r = r < 0 ? 0 : (r > IMG_H - 1 ? IMG_H - 1 : r);  // clamp; w==0 on OOB taps
            acc += w[t] * s_mid[r * MIDSTRIDE + ow];
        }
        dst[idx] = acc;
    }
}

extern "C" void kernel_launch(void* const* d_in, const int* in_sizes, int n_in,
                              void* d_out, int out_size, void* d_ws, size_t ws_size,
                              hipStream_t stream) {
    const float* x = (const float*)d_in[0];   // (2048, 6, 128, 96) fp32
    // d_in[1] (y) is unused by the forward pass.
    float* out = (float*)d_out;               // (2048*6*768,) fp32
    const int n_img = 2048 * 6;
    resize_aa_kernel<<<n_img, 256, 0, stream>>>(x, out);
}